// Round 14
// baseline (153.308 us; speedup 1.0000x reference)
//
#include <hip/hip_runtime.h>
#include <hip/hip_bf16.h>

#define SVOL 110592   // 48*48*48 voxels
#define HD   2304     // 48*48
#define NDIM 48

typedef __attribute__((ext_vector_type(4))) float f32x4;
typedef __attribute__((ext_vector_type(8))) short bf16x8;
typedef unsigned short ushort_t;
typedef unsigned int uint_t;

// ---------------- Kernel 0: W fp32 -> bf16 ----------------
__global__ __launch_bounds__(256) void wconv_kernel(const float* __restrict__ W,
                                                    ushort_t* __restrict__ Wb) {
    int i = blockIdx.x * 256 + threadIdx.x;   // 128*256 = 32768 exactly
    float f = W[i];
    __hip_bfloat16 h = __float2bfloat16(f);
    Wb[i] = *(ushort_t*)&h;
}

// ---------------- Kernel 1: parity-min tables via LDS-staged plane quads ----------------
// tabDp[part][bc][p][h*48+w] (partial), tabH[bc][p][d*48+w], tabW[bc][p][d*48+h]
__global__ __launch_bounds__(256) void tables_kernel(const float* __restrict__ x,
                                                     float* __restrict__ tabDp,
                                                     float* __restrict__ tabH,
                                                     float* __restrict__ tabW) {
    __shared__ __align__(16) float sl[4 * HD];   // 36 KB: 4 planes, linear
    const int bc   = blockIdx.x;
    const int part = blockIdx.y;     // 0..2
    const float* __restrict__ xp = x + (size_t)bc * SVOL + (size_t)part * 16 * HD;
    const int t    = threadIdx.x;
    const int w4   = t >> 6;         // wave 0..3
    const int lane = t & 63;
    const int dlh  = t / NDIM;       // H/W task split (t < 192): plane-local d
    const int wh   = t - dlh * NDIM; // 0..47

    f32x4 accD[3][2];
    #pragma unroll
    for (int s = 0; s < 3; ++s)
        #pragma unroll
        for (int p = 0; p < 2; ++p)
            #pragma unroll
            for (int e = 0; e < 4; ++e) accD[s][p][e] = 3e38f;

    for (int q = 0; q < 4; ++q) {
        const float* __restrict__ qp = xp + (size_t)q * 4 * HD;
        #pragma unroll
        for (int k = 0; k < 9; ++k) {
            const int i16 = (k * 4 + w4) * 64 + lane;
            __builtin_amdgcn_global_load_lds(
                (const __attribute__((address_space(1))) void*)(qp + (size_t)i16 * 4),
                (__attribute__((address_space(3))) void*)&sl[(k * 4 + w4) * 256],
                16, 0, 0);
        }
        __syncthreads();

        #pragma unroll
        for (int s = 0; s < 3; ++s) {
            const int j = t + s * 256;
            if (j < 576) {
                #pragma unroll
                for (int dl = 0; dl < 4; ++dl) {
                    f32x4 v = ((const f32x4*)sl)[dl * 576 + j];
                    #pragma unroll
                    for (int e = 0; e < 4; ++e)
                        accD[s][dl & 1][e] = fminf(accD[s][dl & 1][e], v[e]);
                }
            }
        }
        if (t < 192) {
            const int d = part * 16 + q * 4 + dlh;
            {   // H: min over h at fixed (dlh, w=wh)
                const float* pb = sl + dlh * HD + wh;
                float m0 = 3e38f, m1 = 3e38f;
                #pragma unroll
                for (int h = 0; h < NDIM; h += 2) {
                    m0 = fminf(m0, pb[h * NDIM]);
                    m1 = fminf(m1, pb[(h + 1) * NDIM]);
                }
                tabH[(size_t)bc * 2 * HD + d * NDIM + wh]      = m0;
                tabH[(size_t)bc * 2 * HD + HD + d * NDIM + wh] = m1;
            }
            {   // W: min over w at fixed (dlh, h=wh)
                const f32x4* pr = (const f32x4*)(sl + dlh * HD + wh * NDIM);
                const int rot = wh % 12;
                float m0 = 3e38f, m1 = 3e38f;
                #pragma unroll
                for (int j = 0; j < 12; ++j) {
                    int jj = j + rot; if (jj >= 12) jj -= 12;
                    f32x4 v = pr[jj];
                    m0 = fminf(m0, fminf(v[0], v[2]));
                    m1 = fminf(m1, fminf(v[1], v[3]));
                }
                tabW[(size_t)bc * 2 * HD + d * NDIM + wh]      = m0;
                tabW[(size_t)bc * 2 * HD + HD + d * NDIM + wh] = m1;
            }
        }
        __syncthreads();
    }

    float* tDo = tabDp + ((size_t)part * 256 + bc) * 2 * HD;
    #pragma unroll
    for (int s = 0; s < 3; ++s) {
        const int j = t + s * 256;
        if (j < 576) {
            *((f32x4*)(tDo + j * 4))      = accD[s][0];
            *((f32x4*)(tDo + HD + j * 4)) = accD[s][1];
        }
    }
}

// ---------------- Kernel 2: merge 3 tabD partials -> tabD ----------------
__global__ __launch_bounds__(256) void merge_kernel(const float* __restrict__ tabDp,
                                                    float* __restrict__ tabD) {
    const int i = blockIdx.x * 256 + threadIdx.x;    // f32x4 id, 294912 total
    f32x4 a  = ((const f32x4*)tabDp)[i];
    f32x4 d1 = ((const f32x4*)(tabDp + (size_t)256 * 2 * HD))[i];
    f32x4 d2 = ((const f32x4*)(tabDp + (size_t)2 * 256 * 2 * HD))[i];
    f32x4 m;
    #pragma unroll
    for (int j = 0; j < 4; ++j) m[j] = fminf(a[j], fminf(d1[j], d2[j]));
    ((f32x4*)tabD)[i] = m;
}

// ---------------- Kernel 3: element pass -> yfrag (MFMA A-fragment layout) ----------------
// yfrag[b][stile=s>>4][kk=c>>5][lane=((c&31)>>3)*16+(s&15)][j=c&7] bf16.
__global__ __launch_bounds__(256) void elem_frag_kernel(const float* __restrict__ x,
                                                        const float* __restrict__ tabD,
                                                        const float* __restrict__ tabH,
                                                        const float* __restrict__ tabW,
                                                        ushort_t* __restrict__ yfrag) {
    const int t   = threadIdx.x;
    const int s   = blockIdx.x * 256 + t;      // 432*256 = SVOL exactly
    const int bco = blockIdx.y;                // b*16 + co
    const int b   = bco >> 4, co = bco & 15;
    const int c8  = co * 8;

    const int d = s / HD, r = s - d * HD;
    const int h = r / NDIM, w = r - h * NDIM;
    const int pd = d & 1, ph = h & 1, pw = w & 1;

    const size_t dhw = (size_t)d * NDIM;
    union { ushort_t u8[8]; uint4 v; } px, pj;
    #pragma unroll
    for (int j = 0; j < 8; ++j) {
        const int c = c8 + j;
        const size_t tb = (size_t)(b * 128 + c) * 2 * HD;
        const float xv = x[(size_t)(b * 128 + c) * SVOL + s];
        const float mD = tabD[tb + (size_t)pd * HD + r];
        const float mH = tabH[tb + (size_t)ph * HD + dhw + w];
        const float mW = tabW[tb + (size_t)pw * HD + dhw + h];
        const float mm = fminf(mD, fminf(mH, mW));
        __hip_bfloat16 hx = __float2bfloat16(xv);
        __hip_bfloat16 hj = __float2bfloat16(fmaxf(0.0f, xv - mm));
        px.u8[j] = *(ushort_t*)&hx;
        pj.u8[j] = *(ushort_t*)&hj;
    }

    const int kk = co >> 2, l4 = co & 3;
    const size_t ux = (((size_t)(b * 6912 + (s >> 4))) * 8 + kk) * 512
                    + (size_t)(l4 * 16 + (s & 15)) * 8;
    *(uint4*)&yfrag[ux]        = px.v;   // x half:  kk 0..3
    *(uint4*)&yfrag[ux + 2048] = pj.v;   // xj half: kk+4 (4*512 ushorts)
}

// ---------------- Kernel 4: GEMM, direct fragment loads, 4-deep register pipeline ----------------
// No LDS, no barriers. Round 13 showed VGPR=60 => compiler scheduled a-loads
// just-in-time (1 batch in flight, latency-bound at 2.4 TB/s). Fix: named
// 4-deep fragment buffers; 3-4 x 4-load batches in flight during every MFMA
// cluster. All indices static (rule #20). No launch_bounds min-waves => no
// spill by construction; ~120 VGPR -> 4 waves/SIMD.
__global__ __launch_bounds__(256) void gemm_direct_kernel(const ushort_t* __restrict__ yfrag,
                                                          const ushort_t* __restrict__ Wb,
                                                          const float* __restrict__ bias,
                                                          float* __restrict__ out) {
    const int bx = blockIdx.x;               // 0..1727 (s-tile of 64)
    const int b  = blockIdx.y;
    const int t  = threadIdx.x;
    const int wid = t >> 6, lane = t & 63;
    const int l15 = lane & 15, l4 = lane >> 4;
    const int s0 = bx * 64, st0 = s0 >> 4;

    const ushort_t* __restrict__ ybase =
        yfrag + ((size_t)b * 6912 + st0) * 8 * 512 + (size_t)lane * 8;
    const ushort_t* __restrict__ wp = Wb + (size_t)(wid * 32 + l15) * 256 + l4 * 8;

    f32x4 acc[4][2] = {};
    bf16x8 aA[4], aB[4], aC[4], aD[4];

#define LOADA(buf, kk)                                                          \
    { _Pragma("unroll")                                                         \
      for (int n = 0; n < 4; ++n)                                               \
          buf[n] = *(const bf16x8*)(ybase + ((size_t)n * 8 + (kk)) * 512); }
#define DOMFMA(buf, kk)                                                         \
    { bf16x8 aw0 = *(const bf16x8*)(wp + (kk) * 32);                            \
      bf16x8 aw1 = *(const bf16x8*)(wp + 16 * 256 + (kk) * 32);                 \
      _Pragma("unroll")                                                         \
      for (int n = 0; n < 4; ++n) {                                             \
          acc[n][0] = __builtin_amdgcn_mfma_f32_16x16x32_bf16(buf[n], aw0, acc[n][0], 0, 0, 0); \
          acc[n][1] = __builtin_amdgcn_mfma_f32_16x16x32_bf16(buf[n], aw1, acc[n][1], 0, 0, 0); \
      } }

    LOADA(aA, 0) LOADA(aB, 1) LOADA(aC, 2) LOADA(aD, 3)
    DOMFMA(aA, 0) LOADA(aA, 4)
    DOMFMA(aB, 1) LOADA(aB, 5)
    DOMFMA(aC, 2) LOADA(aC, 6)
    DOMFMA(aD, 3) LOADA(aD, 7)
    DOMFMA(aA, 4)
    DOMFMA(aB, 5)
    DOMFMA(aC, 6)
    DOMFMA(aD, 7)
#undef LOADA
#undef DOMFMA

    float bv[2];
    bv[0] = bias[wid * 32 + l15];
    bv[1] = bias[wid * 32 + 16 + l15];
    float* ob = out + (size_t)b * 128 * SVOL;
    #pragma unroll
    for (int n = 0; n < 4; ++n)
        #pragma unroll
        for (int m = 0; m < 2; ++m) {
            const int o = wid * 32 + m * 16 + l15;
            const int s = s0 + n * 16 + l4 * 4;
            f32x4 r;
            #pragma unroll
            for (int j = 0; j < 4; ++j) r[j] = fmaxf(acc[n][m][j] + bv[m], 0.0f);
            *(f32x4*)(ob + (size_t)o * SVOL + s) = r;
        }
}

extern "C" void kernel_launch(void* const* d_in, const int* in_sizes, int n_in,
                              void* d_out, int out_size, void* d_ws, size_t ws_size,
                              hipStream_t stream) {
    const float* x    = (const float*)d_in[0];
    const float* W    = (const float*)d_in[1];
    const float* bias = (const float*)d_in[2];
    float* out = (float*)d_out;

    // d_ws: yfrag (113.25 MB) | Wb (64 KB)
    ushort_t* yfrag = (ushort_t*)d_ws;
    ushort_t* Wb    = (ushort_t*)((char*)d_ws + (size_t)2 * 256 * SVOL * 2);

    // Tables live in d_out scratch (gemm_direct fully overwrites out afterwards).
    float* tabDp = (float*)d_out;                       // 13.5 MB (3 partials)
    float* tabH  = tabDp + (size_t)3 * 256 * 2 * HD;    // 4.5 MB
    float* tabW  = tabH  + (size_t)256 * 2 * HD;        // 4.5 MB
    float* tabD  = tabW  + (size_t)256 * 2 * HD;        // 4.5 MB (merged)

    wconv_kernel<<<128, 256, 0, stream>>>(W, Wb);
    tables_kernel<<<dim3(256, 3), 256, 0, stream>>>(x, tabDp, tabH, tabW);
    merge_kernel<<<1152, 256, 0, stream>>>(tabDp, tabD);
    elem_frag_kernel<<<dim3(432, 32), 256, 0, stream>>>(x, tabD, tabH, tabW, yfrag);
    gemm_direct_kernel<<<dim3(SVOL / 64, 2), 256, 0, stream>>>(yfrag, Wb, bias, out);
}

// Round 15
// 147.843 us; speedup vs baseline: 1.0370x; 1.0370x over previous
//
#include <hip/hip_runtime.h>
#include <hip/hip_bf16.h>

#define SVOL 110592   // 48*48*48 voxels
#define HD   2304     // 48*48
#define NDIM 48

typedef __attribute__((ext_vector_type(4))) float f32x4;
typedef __attribute__((ext_vector_type(8))) short bf16x8;
typedef unsigned short ushort_t;
typedef unsigned int uint_t;

// ---------------- Kernel 0: W fp32 -> bf16 ----------------
__global__ __launch_bounds__(256) void wconv_kernel(const float* __restrict__ W,
                                                    ushort_t* __restrict__ Wb) {
    int i = blockIdx.x * 256 + threadIdx.x;   // 128*256 = 32768 exactly
    float f = W[i];
    __hip_bfloat16 h = __float2bfloat16(f);
    Wb[i] = *(ushort_t*)&h;
}

// ---------------- Kernel 1: parity-min tables via LDS-staged plane quads ----------------
// tabDp[part][bc][p][h*48+w] (partial), tabH[bc][p][d*48+w], tabW[bc][p][d*48+h]
__global__ __launch_bounds__(256) void tables_kernel(const float* __restrict__ x,
                                                     float* __restrict__ tabDp,
                                                     float* __restrict__ tabH,
                                                     float* __restrict__ tabW) {
    __shared__ __align__(16) float sl[4 * HD];   // 36 KB: 4 planes, linear
    const int bc   = blockIdx.x;
    const int part = blockIdx.y;     // 0..2
    const float* __restrict__ xp = x + (size_t)bc * SVOL + (size_t)part * 16 * HD;
    const int t    = threadIdx.x;
    const int w4   = t >> 6;         // wave 0..3
    const int lane = t & 63;
    const int dlh  = t / NDIM;       // H/W task split (t < 192): plane-local d
    const int wh   = t - dlh * NDIM; // 0..47

    f32x4 accD[3][2];
    #pragma unroll
    for (int s = 0; s < 3; ++s)
        #pragma unroll
        for (int p = 0; p < 2; ++p)
            #pragma unroll
            for (int e = 0; e < 4; ++e) accD[s][p][e] = 3e38f;

    for (int q = 0; q < 4; ++q) {
        const float* __restrict__ qp = xp + (size_t)q * 4 * HD;
        #pragma unroll
        for (int k = 0; k < 9; ++k) {
            const int i16 = (k * 4 + w4) * 64 + lane;
            __builtin_amdgcn_global_load_lds(
                (const __attribute__((address_space(1))) void*)(qp + (size_t)i16 * 4),
                (__attribute__((address_space(3))) void*)&sl[(k * 4 + w4) * 256],
                16, 0, 0);
        }
        __syncthreads();

        #pragma unroll
        for (int s = 0; s < 3; ++s) {
            const int j = t + s * 256;
            if (j < 576) {
                #pragma unroll
                for (int dl = 0; dl < 4; ++dl) {
                    f32x4 v = ((const f32x4*)sl)[dl * 576 + j];
                    #pragma unroll
                    for (int e = 0; e < 4; ++e)
                        accD[s][dl & 1][e] = fminf(accD[s][dl & 1][e], v[e]);
                }
            }
        }
        if (t < 192) {
            const int d = part * 16 + q * 4 + dlh;
            {   // H: min over h at fixed (dlh, w=wh)
                const float* pb = sl + dlh * HD + wh;
                float m0 = 3e38f, m1 = 3e38f;
                #pragma unroll
                for (int h = 0; h < NDIM; h += 2) {
                    m0 = fminf(m0, pb[h * NDIM]);
                    m1 = fminf(m1, pb[(h + 1) * NDIM]);
                }
                tabH[(size_t)bc * 2 * HD + d * NDIM + wh]      = m0;
                tabH[(size_t)bc * 2 * HD + HD + d * NDIM + wh] = m1;
            }
            {   // W: min over w at fixed (dlh, h=wh)
                const f32x4* pr = (const f32x4*)(sl + dlh * HD + wh * NDIM);
                const int rot = wh % 12;
                float m0 = 3e38f, m1 = 3e38f;
                #pragma unroll
                for (int j = 0; j < 12; ++j) {
                    int jj = j + rot; if (jj >= 12) jj -= 12;
                    f32x4 v = pr[jj];
                    m0 = fminf(m0, fminf(v[0], v[2]));
                    m1 = fminf(m1, fminf(v[1], v[3]));
                }
                tabW[(size_t)bc * 2 * HD + d * NDIM + wh]      = m0;
                tabW[(size_t)bc * 2 * HD + HD + d * NDIM + wh] = m1;
            }
        }
        __syncthreads();
    }

    float* tDo = tabDp + ((size_t)part * 256 + bc) * 2 * HD;
    #pragma unroll
    for (int s = 0; s < 3; ++s) {
        const int j = t + s * 256;
        if (j < 576) {
            *((f32x4*)(tDo + j * 4))      = accD[s][0];
            *((f32x4*)(tDo + HD + j * 4)) = accD[s][1];
        }
    }
}

// ---------------- Kernel 2: merge 3 tabD partials -> tabD ----------------
__global__ __launch_bounds__(256) void merge_kernel(const float* __restrict__ tabDp,
                                                    float* __restrict__ tabD) {
    const int i = blockIdx.x * 256 + threadIdx.x;    // f32x4 id, 294912 total
    f32x4 a  = ((const f32x4*)tabDp)[i];
    f32x4 d1 = ((const f32x4*)(tabDp + (size_t)256 * 2 * HD))[i];
    f32x4 d2 = ((const f32x4*)(tabDp + (size_t)2 * 256 * 2 * HD))[i];
    f32x4 m;
    #pragma unroll
    for (int j = 0; j < 4; ++j) m[j] = fminf(a[j], fminf(d1[j], d2[j]));
    ((f32x4*)tabD)[i] = m;
}

// ---------------- Kernel 3: element pass -> yfrag (MFMA A-fragment layout) ----------------
// yfrag[b][stile=s>>4][kk=c>>5][lane=((c&31)>>3)*16+(s&15)][j=c&7] bf16.
__global__ __launch_bounds__(256) void elem_frag_kernel(const float* __restrict__ x,
                                                        const float* __restrict__ tabD,
                                                        const float* __restrict__ tabH,
                                                        const float* __restrict__ tabW,
                                                        ushort_t* __restrict__ yfrag) {
    const int t   = threadIdx.x;
    const int s   = blockIdx.x * 256 + t;      // 432*256 = SVOL exactly
    const int bco = blockIdx.y;                // b*16 + co
    const int b   = bco >> 4, co = bco & 15;
    const int c8  = co * 8;

    const int d = s / HD, r = s - d * HD;
    const int h = r / NDIM, w = r - h * NDIM;
    const int pd = d & 1, ph = h & 1, pw = w & 1;

    const size_t dhw = (size_t)d * NDIM;
    union { ushort_t u8[8]; uint4 v; } px, pj;
    #pragma unroll
    for (int j = 0; j < 8; ++j) {
        const int c = c8 + j;
        const size_t tb = (size_t)(b * 128 + c) * 2 * HD;
        const float xv = x[(size_t)(b * 128 + c) * SVOL + s];
        const float mD = tabD[tb + (size_t)pd * HD + r];
        const float mH = tabH[tb + (size_t)ph * HD + dhw + w];
        const float mW = tabW[tb + (size_t)pw * HD + dhw + h];
        const float mm = fminf(mD, fminf(mH, mW));
        __hip_bfloat16 hx = __float2bfloat16(xv);
        __hip_bfloat16 hj = __float2bfloat16(fmaxf(0.0f, xv - mm));
        px.u8[j] = *(ushort_t*)&hx;
        pj.u8[j] = *(ushort_t*)&hj;
    }

    const int kk = co >> 2, l4 = co & 3;
    const size_t ux = (((size_t)(b * 6912 + (s >> 4))) * 8 + kk) * 512
                    + (size_t)(l4 * 16 + (s & 15)) * 8;
    *(uint4*)&yfrag[ux]        = px.v;   // x half:  kk 0..3
    *(uint4*)&yfrag[ux + 2048] = pj.v;   // xj half: kk+4 (4*512 ushorts)
}

// ---------------- Kernel 4: GEMM, asm-pipelined fragment loads (T3/T4 pattern) ----------------
// No LDS, no barriers. Round 14 proved plain-HIP load pipelining is re-sunk by
// the compiler (VGPR stayed 64). Here ALL hot-loop vmem is inline asm:
// 8 batches of {4 a-frag + 2 W-frag} global_load_dwordx4, 3-deep rotation,
// counted s_waitcnt vmcnt(12/6/0) (never 0 mid-loop) + sched_barrier after
// each wait (rule #18). ~130 VGPR, no launch_bounds cap -> no spill.
__global__ __launch_bounds__(256) void gemm_direct_kernel(const ushort_t* __restrict__ yfrag,
                                                          const ushort_t* __restrict__ Wb,
                                                          const float* __restrict__ bias,
                                                          float* __restrict__ out) {
    const int bx = blockIdx.x;               // 0..1727 (s-tile of 64)
    const int b  = blockIdx.y;
    const int t  = threadIdx.x;
    const int wid = t >> 6, lane = t & 63;
    const int l15 = lane & 15, l4 = lane >> 4;
    const int s0 = bx * 64, st0 = s0 >> 4;

    const ushort_t* __restrict__ ybase =
        yfrag + ((size_t)b * 6912 + st0) * 8 * 512 + (size_t)lane * 8;
    const ushort_t* __restrict__ wp = Wb + (size_t)(wid * 32 + l15) * 256 + l4 * 8;

    f32x4 acc[4][2] = {};
    bf16x8 a0A, a1A, a2A, a3A, w0A, w1A;
    bf16x8 a0B, a1B, a2B, a3B, w0B, w1B;
    bf16x8 a0C, a1C, a2C, a3C, w0C, w1C;

#define GLOAD(dst, p) \
    asm volatile("global_load_dwordx4 %0, %1, off" : "=v"(dst) : "v"(p) : "memory");
#define LOADB(S, kk)                                     \
    GLOAD(a0##S, ybase + (size_t)((0 * 8 + (kk)) * 512)) \
    GLOAD(a1##S, ybase + (size_t)((1 * 8 + (kk)) * 512)) \
    GLOAD(a2##S, ybase + (size_t)((2 * 8 + (kk)) * 512)) \
    GLOAD(a3##S, ybase + (size_t)((3 * 8 + (kk)) * 512)) \
    GLOAD(w0##S, wp + (size_t)((kk) * 32))               \
    GLOAD(w1##S, wp + (size_t)(16 * 256 + (kk) * 32))
#define WAITV(N)                                              \
    asm volatile("s_waitcnt vmcnt(" #N ")" ::: "memory");     \
    __builtin_amdgcn_sched_barrier(0);
#define DOMFMA(S)                                                                          \
    acc[0][0] = __builtin_amdgcn_mfma_f32_16x16x32_bf16(a0##S, w0##S, acc[0][0], 0, 0, 0); \
    acc[0][1] = __builtin_amdgcn_mfma_f32_16x16x32_bf16(a0##S, w1##S, acc[0][1], 0, 0, 0); \
    acc[1][0] = __builtin_amdgcn_mfma_f32_16x16x32_bf16(a1##S, w0##S, acc[1][0], 0, 0, 0); \
    acc[1][1] = __builtin_amdgcn_mfma_f32_16x16x32_bf16(a1##S, w1##S, acc[1][1], 0, 0, 0); \
    acc[2][0] = __builtin_amdgcn_mfma_f32_16x16x32_bf16(a2##S, w0##S, acc[2][0], 0, 0, 0); \
    acc[2][1] = __builtin_amdgcn_mfma_f32_16x16x32_bf16(a2##S, w1##S, acc[2][1], 0, 0, 0); \
    acc[3][0] = __builtin_amdgcn_mfma_f32_16x16x32_bf16(a3##S, w0##S, acc[3][0], 0, 0, 0); \
    acc[3][1] = __builtin_amdgcn_mfma_f32_16x16x32_bf16(a3##S, w1##S, acc[3][1], 0, 0, 0);

    LOADB(A, 0) LOADB(B, 1) LOADB(C, 2)          // 18 outstanding
    WAITV(12) DOMFMA(A) LOADB(A, 3)              // batch0 done; issue 3
    WAITV(12) DOMFMA(B) LOADB(B, 4)
    WAITV(12) DOMFMA(C) LOADB(C, 5)
    WAITV(12) DOMFMA(A) LOADB(A, 6)
    WAITV(12) DOMFMA(B) LOADB(B, 7)
    WAITV(12) DOMFMA(C)                          // batch5 done; 6,7 in flight
    WAITV(6)  DOMFMA(A)                          // batch6 done
    WAITV(0)  DOMFMA(B)                          // batch7 done
#undef GLOAD
#undef LOADB
#undef WAITV
#undef DOMFMA

    float bv[2];
    bv[0] = bias[wid * 32 + l15];
    bv[1] = bias[wid * 32 + 16 + l15];
    float* ob = out + (size_t)b * 128 * SVOL;
    #pragma unroll
    for (int n = 0; n < 4; ++n)
        #pragma unroll
        for (int m = 0; m < 2; ++m) {
            const int o = wid * 32 + m * 16 + l15;
            const int s = s0 + n * 16 + l4 * 4;
            f32x4 r;
            #pragma unroll
            for (int j = 0; j < 4; ++j) r[j] = fmaxf(acc[n][m][j] + bv[m], 0.0f);
            *(f32x4*)(ob + (size_t)o * SVOL + s) = r;
        }
}

extern "C" void kernel_launch(void* const* d_in, const int* in_sizes, int n_in,
                              void* d_out, int out_size, void* d_ws, size_t ws_size,
                              hipStream_t stream) {
    const float* x    = (const float*)d_in[0];
    const float* W    = (const float*)d_in[1];
    const float* bias = (const float*)d_in[2];
    float* out = (float*)d_out;

    // d_ws: yfrag (113.25 MB) | Wb (64 KB)
    ushort_t* yfrag = (ushort_t*)d_ws;
    ushort_t* Wb    = (ushort_t*)((char*)d_ws + (size_t)2 * 256 * SVOL * 2);

    // Tables live in d_out scratch (gemm_direct fully overwrites out afterwards).
    float* tabDp = (float*)d_out;                       // 13.5 MB (3 partials)
    float* tabH  = tabDp + (size_t)3 * 256 * 2 * HD;    // 4.5 MB
    float* tabW  = tabH  + (size_t)256 * 2 * HD;        // 4.5 MB
    float* tabD  = tabW  + (size_t)256 * 2 * HD;        // 4.5 MB (merged)

    wconv_kernel<<<128, 256, 0, stream>>>(W, Wb);
    tables_kernel<<<dim3(256, 3), 256, 0, stream>>>(x, tabDp, tabH, tabW);
    merge_kernel<<<1152, 256, 0, stream>>>(tabDp, tabD);
    elem_frag_kernel<<<dim3(432, 32), 256, 0, stream>>>(x, tabD, tabH, tabW, yfrag);
    gemm_direct_kernel<<<dim3(SVOL / 64, 2), 256, 0, stream>>>(yfrag, Wb, bias, out);
}